// Round 1
// 2347.272 us; speedup vs baseline: 1.2379x; 1.2379x over previous
//
#include <hip/hip_runtime.h>
#include <hip/hip_bf16.h>

typedef __hip_bfloat16 bf16;
typedef __attribute__((ext_vector_type(4))) float f32x4;
typedef __attribute__((ext_vector_type(8))) short short8;

#define TOT   8192      // B*S (single pass)
#define SEQ   4096
#define NHD   16
#define HD    128
#define C2    2048
#define CHK   64
#define NCPB  64        // chunks per (batch,head)
#define SW    16        // dv slice width in stage2
#define QSCALE 0.08838834764831845f

__device__ __forceinline__ float b2f(bf16 x){ return __bfloat162float(x); }
__device__ __forceinline__ bf16  f2b(float x){ return __float2bfloat16(x); }
__device__ __forceinline__ float expn(float x){ return __expf(fminf(x, 0.f)); }
__device__ __forceinline__ short bts(float x){
  bf16 b = f2b(x); short s; __builtin_memcpy(&s, &b, 2); return s;
}
__device__ __forceinline__ float s2f(short v){
  unsigned int u = ((unsigned int)(unsigned short)v) << 16;
  float f; __builtin_memcpy(&f, &u, 4); return f;
}

// ---------------------------------------------------------------------------
// Device-global scratch
// ---------------------------------------------------------------------------
__device__ __attribute__((aligned(16))) unsigned short G_xb  [TOT*C2];
__device__ __attribute__((aligned(16))) unsigned short G_qlin[TOT*C2];
__device__ __attribute__((aligned(16))) unsigned short G_klin[TOT*C2];
__device__ __attribute__((aligned(16))) unsigned short G_vlin[TOT*C2];
__device__ __attribute__((aligned(16))) unsigned short G_qb  [TOT*C2];
__device__ __attribute__((aligned(16))) unsigned short G_kb  [TOT*C2];
__device__ __attribute__((aligned(16))) unsigned short G_vb  [TOT*C2];
__device__ __attribute__((aligned(16))) unsigned short G_qg  [TOT*C2];
__device__ __attribute__((aligned(16))) unsigned short G_gate[TOT*C2];
__device__ __attribute__((aligned(16))) unsigned short G_core[TOT*C2];
__device__ __attribute__((aligned(16))) unsigned short G_opre[TOT*C2];
__device__ __attribute__((aligned(16))) float          G_g   [TOT*C2];
__device__ __attribute__((aligned(16))) unsigned short G_attn[2048*CHK*CHK];
__device__ __attribute__((aligned(16))) unsigned short G_ktt [2048*CHK*HD];
__device__ __attribute__((aligned(16))) float          G_egl [2048*HD];
__device__ __attribute__((aligned(16))) float          G_beta[TOT*NHD];
__device__ __attribute__((aligned(16))) float          G_fa  [TOT*HD];
__device__ __attribute__((aligned(16))) unsigned short G_ga  [TOT*HD];
__device__ __attribute__((aligned(16))) unsigned short G_Wqt [C2*C2];
__device__ __attribute__((aligned(16))) unsigned short G_Wkt [C2*C2];
__device__ __attribute__((aligned(16))) unsigned short G_Wvt [C2*C2];
__device__ __attribute__((aligned(16))) unsigned short G_Wot [C2*C2];
__device__ __attribute__((aligned(16))) unsigned short G_Wgat[HD*C2];

#define P_QLIN ((bf16*)G_qlin)
#define P_KLIN ((bf16*)G_klin)
#define P_VLIN ((bf16*)G_vlin)
#define P_QB   ((bf16*)G_qb)
#define P_KB   ((bf16*)G_kb)
#define P_VB   ((bf16*)G_vb)
#define P_QG   ((bf16*)G_qg)
#define P_GATE ((bf16*)G_gate)
#define P_CORE ((bf16*)G_core)
#define P_OPRE ((bf16*)G_opre)
#define P_ATTN ((bf16*)G_attn)
#define P_KTT  ((bf16*)G_ktt)

__device__ __forceinline__ const bf16* selWt(int s){
  switch(s){ case 0: return (const bf16*)G_Wqt; case 1: return (const bf16*)G_Wkt;
             case 2: return (const bf16*)G_Wvt; case 3: return (const bf16*)G_Wot; }
  return (const bf16*)G_Wgat;
}
__device__ __forceinline__ bf16* selCm(int s){
  switch(s){ case 0: return P_QLIN; case 1: return P_KLIN;
             case 2: return P_VLIN; }
  return (bf16*)G_ga;
}
__device__ __forceinline__ const void* selA_thin(int s){
  switch(s){ case 0: return G_fa; case 1: return G_ga; }
  return nullptr;
}
__device__ __forceinline__ void* selC_thin(int s){
  switch(s){ case 0: return G_beta; case 1: return G_fa;
             case 2: return G_g; }
  return G_gate;
}

// ---------------------------------------------------------------------------
// Weight transpose+convert: W f32 [K=2048][N] -> Wt bf16 [N][2048].
// Grid (N/64, 32), 256 thr.
// ---------------------------------------------------------------------------
__global__ void __launch_bounds__(256) wconv_t_k(const float* __restrict__ W,
                                                 int outSel, int N)
{
  __shared__ float tile[64][65];
  const int t = threadIdx.x;
  const int n0 = blockIdx.x*64, k0 = blockIdx.y*64;
  const int c4 = (t&15)*4, rr = t>>4;
  #pragma unroll
  for (int i=0;i<4;i++){
    const float* src = W + (size_t)(k0+rr+16*i)*N + n0 + c4;
    float4 f = *(const float4*)src;
    tile[rr+16*i][c4+0]=f.x; tile[rr+16*i][c4+1]=f.y;
    tile[rr+16*i][c4+2]=f.z; tile[rr+16*i][c4+3]=f.w;
  }
  __syncthreads();
  bf16* out = (bf16*)(outSel==0?G_Wqt:outSel==1?G_Wkt:outSel==2?G_Wvt:
                      outSel==3?G_Wot:G_Wgat);
  const int nr = t>>3, kc = (t&7)*8;
  #pragma unroll
  for (int p=0;p<2;p++){
    int n = p*32 + nr;
    __attribute__((aligned(16))) bf16 tmp[8];
    #pragma unroll
    for (int j=0;j<8;j++) tmp[j] = f2b(tile[kc+j][n]);
    *(float4*)(out + (size_t)(n0+n)*C2 + k0 + kc) = *(const float4*)tmp;
  }
}

// x f32 -> G_xb bf16
__global__ void __launch_bounds__(256) xconv_k(const float* __restrict__ x)
{
  size_t idx = ((size_t)blockIdx.x*256 + threadIdx.x)*8;
  const float* src = x + idx;
  float4 f0 = *(const float4*)src, f1 = *(const float4*)(src+4);
  __attribute__((aligned(16))) bf16 tmp[8];
  tmp[0]=f2b(f0.x); tmp[1]=f2b(f0.y); tmp[2]=f2b(f0.z); tmp[3]=f2b(f0.w);
  tmp[4]=f2b(f1.x); tmp[5]=f2b(f1.y); tmp[6]=f2b(f1.z); tmp[7]=f2b(f1.w);
  *(float4*)((bf16*)G_xb + idx) = *(const float4*)tmp;
}

// ---------------------------------------------------------------------------
// MFMA GEMM: C[M,N] = A[M,K=2048] @ Bt[N,K]^T, bf16 in, f32 acc.
// 128x128 tile, BK=32, 4 waves x (64x64).
// outMode 0: bf16 -> selCm(cSel), stride N.  outMode 1: f32 -> Cw, stride N.
// ---------------------------------------------------------------------------
template<int OUTMODE>
__global__ void __launch_bounds__(256) gemm_mfma(
    int aSel, int bSel, int cSel, float* __restrict__ Cw, int N)
{
  const bf16* A  = (aSel==0) ? (const bf16*)G_xb : (const bf16*)G_opre;
  const bf16* Bt = selWt(bSel);
  __shared__ bf16 As[128*40];
  __shared__ bf16 Bs[128*40];
  const int t  = threadIdx.x;
  const int l  = t & 63;
  const int wv = t >> 6;
  const int wm = (wv>>1)*64, wn = (wv&1)*64;
  const int bm = blockIdx.y*128, bn = blockIdx.x*128;
  const int lr = l & 15;
  const int lk = (l>>4)*8;
  const int sr = t>>1, sc = (t&1)*16;

  f32x4 acc[4][4];
  #pragma unroll
  for (int i=0;i<4;i++)
    #pragma unroll
    for (int j=0;j<4;j++)
      #pragma unroll
      for (int v=0;v<4;v++) acc[i][j][v] = 0.f;

  for (int k0=0; k0<C2; k0+=32){
    const bf16* ga = A  + (size_t)(bm+sr)*C2 + k0 + sc;
    const bf16* gb = Bt + (size_t)(bn+sr)*C2 + k0 + sc;
    float4 a0 = *(const float4*)ga; float4 a1 = *(const float4*)(ga+8);
    float4 b0 = *(const float4*)gb; float4 b1 = *(const float4*)(gb+8);
    __syncthreads();
    *(float4*)&As[sr*40+sc]   = a0; *(float4*)&As[sr*40+sc+8] = a1;
    *(float4*)&Bs[sr*40+sc]   = b0; *(float4*)&Bs[sr*40+sc+8] = b1;
    __syncthreads();
    short8 af[4], bfr[4];
    #pragma unroll
    for (int i=0;i<4;i++){
      af[i]  = *(const short8*)&As[(wm+i*16+lr)*40 + lk];
      bfr[i] = *(const short8*)&Bs[(wn+i*16+lr)*40 + lk];
    }
    #pragma unroll
    for (int i=0;i<4;i++)
      #pragma unroll
      for (int j=0;j<4;j++)
        acc[i][j] = __builtin_amdgcn_mfma_f32_16x16x32_bf16(af[i], bfr[j], acc[i][j], 0, 0, 0);
  }

  bf16* Cb = (OUTMODE==0) ? selCm(cSel) : nullptr;
  #pragma unroll
  for (int i=0;i<4;i++){
    #pragma unroll
    for (int v=0;v<4;v++){
      int r = bm + wm + i*16 + (l>>4)*4 + v;
      #pragma unroll
      for (int j=0;j<4;j++){
        int col = bn + wn + j*16 + (l&15);
        float val = acc[i][j][v];
        if (OUTMODE==1) Cw[(size_t)r*N + col] = val;
        else            Cb[(size_t)r*N + col] = f2b(val);
      }
    }
  }
}

// ---------------------------------------------------------------------------
// VALU thin GEMM: C[M,N] = A[M,K] @ B[K,N], B f32 weights.
// ---------------------------------------------------------------------------
template<typename AT, int OUT_BF16, int ACT_SIG>
__global__ void __launch_bounds__(256) gemm_k(
    const AT* __restrict__ Ap, int aSel, const float* __restrict__ Bm,
    const float* __restrict__ bias, int cSel, int M, int N, int K)
{
  const AT* A = (aSel < 0) ? Ap : (const AT*)selA_thin(aSel);
  void* Cv = selC_thin(cSel);

  __shared__ float As[128][17];
  __shared__ float Bs[16][129];
  const int tx = threadIdx.x, ty = threadIdx.y;
  const int tid = ty*16 + tx;
  const int bm = blockIdx.y * 128, bn = blockIdx.x * 128;

  float acc[8][8];
  #pragma unroll
  for (int i=0;i<8;i++)
    #pragma unroll
    for (int j=0;j<8;j++) acc[i][j]=0.f;

  for (int k0=0; k0<K; k0+=16) {
    { int r = tid >> 1, c = (tid & 1)*8;
      const AT* src = A + (size_t)(bm+r)*K + k0 + c;
      if constexpr (sizeof(AT) == 2) {
        float4 f = *(const float4*)src;
        const bf16* e = (const bf16*)&f;
        #pragma unroll
        for (int u=0;u<8;u++) As[r][c+u] = b2f(e[u]);
      } else {
        float4 f0 = *(const float4*)src;
        float4 f1 = *(const float4*)(src+4);
        As[r][c+0]=f0.x; As[r][c+1]=f0.y; As[r][c+2]=f0.z; As[r][c+3]=f0.w;
        As[r][c+4]=f1.x; As[r][c+5]=f1.y; As[r][c+6]=f1.z; As[r][c+7]=f1.w;
      }
    }
    { int r = tid >> 4, c = (tid & 15)*8;
      int gn = bn + c;
      const float* src = Bm + (size_t)(k0+r)*N + gn;
      if (gn + 7 < N) {
        float4 f0 = *(const float4*)src;
        float4 f1 = *(const float4*)(src+4);
        Bs[r][c+0]=f0.x; Bs[r][c+1]=f0.y; Bs[r][c+2]=f0.z; Bs[r][c+3]=f0.w;
        Bs[r][c+4]=f1.x; Bs[r][c+5]=f1.y; Bs[r][c+6]=f1.z; Bs[r][c+7]=f1.w;
      } else {
        #pragma unroll
        for (int u=0;u<8;u++)
          Bs[r][c+u] = (gn+u < N) ? src[u] : 0.f;
      }
    }
    __syncthreads();
    #pragma unroll
    for (int kk=0;kk<16;kk++){
      float a[8], b[8];
      #pragma unroll
      for (int i=0;i<8;i++) a[i] = As[ty + 16*i][kk];
      #pragma unroll
      for (int j=0;j<8;j++) b[j] = Bs[kk][tx + 16*j];
      #pragma unroll
      for (int i=0;i<8;i++)
        #pragma unroll
        for (int j=0;j<8;j++) acc[i][j] += a[i]*b[j];
    }
    __syncthreads();
  }
  #pragma unroll
  for (int i=0;i<8;i++){
    int m = bm + ty + 16*i;
    #pragma unroll
    for (int j=0;j<8;j++){
      int n = bn + tx + 16*j;
      if (n < N) {
        float v = acc[i][j];
        if (bias) v += bias[n];
        if (ACT_SIG) v = 1.f/(1.f + __expf(-v));
        if (OUT_BF16) ((bf16*)Cv)[(size_t)m*N + n] = f2b(v);
        else          ((float*)Cv)[(size_t)m*N + n] = v;
      }
    }
  }
}

// ---------------------------------------------------------------------------
// Causal depthwise conv (K=4) + SiLU + optional l2norm. Grid TOT.
// ---------------------------------------------------------------------------
__global__ void __launch_bounds__(256) conv_silu_k(
    int sel, const float* __restrict__ kern, int do_norm)
{
  const bf16* lin = sel==0 ? P_QLIN : sel==1 ? P_KLIN : P_VLIN;
  bf16*       out = sel==0 ? P_QB   : sel==1 ? P_KB   : P_VB;

  __shared__ float part[256];
  __shared__ float scal[16];
  const int t = threadIdx.x;
  const int r = blockIdx.x;
  const int s = r & (SEQ-1);
  const int c0 = t*8;
  float v[8];
  #pragma unroll
  for (int u=0;u<8;u++) v[u]=0.f;
  for (int j=0;j<4;j++){
    int sp = s - 3 + j;
    if (sp < 0) continue;
    const bf16* row = lin + (size_t)(r-3+j)*C2 + c0;
    const float* kr = kern + j*C2 + c0;
    #pragma unroll
    for (int u=0;u<8;u++) v[u] += b2f(row[u]) * kr[u];
  }
  #pragma unroll
  for (int u=0;u<8;u++){ float x=v[u]; v[u] = x / (1.f + __expf(-x)); }
  if (do_norm) {
    float ss=0.f;
    #pragma unroll
    for (int u=0;u<8;u++) ss += v[u]*v[u];
    part[t]=ss; __syncthreads();
    if (t<16){
      float s2=0.f;
      for (int i=0;i<16;i++) s2 += part[t*16+i];
      scal[t] = rsqrtf(s2 + 1e-6f);
    }
    __syncthreads();
    float sc = scal[t>>4];
    #pragma unroll
    for (int u=0;u<8;u++) v[u] *= sc;
  }
  bf16* orow = out + (size_t)r*C2 + c0;
  #pragma unroll
  for (int u=0;u<8;u++) orow[u] = f2b(v[u]);
}

// g = -exp(A_log[h]) * softplus(g_lin)
__global__ void __launch_bounds__(256) g_transform_k(const float* __restrict__ A_log)
{
  size_t i = (size_t)blockIdx.x*256 + threadIdx.x;
  float x = fminf(G_g[i], 80.f);
  int h = (int)((i >> 7) & (NHD-1));
  float a = __expf(A_log[h]);
  float sp = (x > 20.f) ? x : log1pf(__expf(x));
  G_g[i] = -a * sp;
}

// Per-chunk cumsum. Grid 2048 x 128.
__global__ void __launch_bounds__(128) gcum_k()
{
  const int blk = blockIdx.x;
  const int icg = blk & 127, h = blk >> 7;
  const int d = threadIdx.x;
  size_t gi = (size_t)(icg*CHK)*C2 + h*HD + d;
  float a = 0.f;
  for (int r=0;r<CHK;r++){ a += G_g[gi]; G_g[gi] = a; gi += C2; }
}

// ---------------------------------------------------------------------------
// Stage 1 (MFMA rewrite): grid 2048 (h*128+icg), 512 thr = 8 waves.
// Block-reference decomposition:  e^{g_i-g_j} = e^{g_i-r_I} e^{r_I-r_{J+1}}
//                                               e^{r_{J+1}-g_j}  (all <= 1)
// Off-diagonal 16x16 block pairs of A/attn -> mfma_16x16x32_bf16 on
// prescaled operands. Diagonal 16x16 blocks -> direct VALU (exact).
// Solves: invert 4 diag blocks once (64-lane serial), then blocked
// parallel forward substitution with f32 MACs.
// Outputs identical to before: attn, u->vb, w->qb, qg, egl, ktt.
// ---------------------------------------------------------------------------
__global__ void __launch_bounds__(512, 4) stage1_k()
{
  __shared__ __attribute__((aligned(16))) char sm[63872];
  bf16*  kT   = (bf16*)sm;                 // [64][136] raw k -> aK (in place)
  bf16*  qT   = (bf16*)(sm+17408);         // [64][136] raw q -> aQ (in place)
  float* AmD  = (float*)(sm+17408);        // [4][16][17]  (post-P1, over qT)
  float* AmL  = (float*)(sm+21760);        // [6][16][17]  (post-P1, over qT)
  float* gH   = (float*)(sm+34816);        // [64][38] quarter-d g (passes)
  float* Dinv = (float*)(sm+34816);        // [4][16][17]  (post-pass, over gH)
  bf16*  cJ   = (bf16*)(sm+44544);         // [48][136] k*e^{r_{J+1}-g}
  float* rhs  = (float*)(sm+44544);        // [64][66] solve buffer (over cJ+rS)
  float* rS   = (float*)(sm+57600);        // [4][132] ref rows of g
  float* er   = (float*)(sm+61440);        // [4][132] exp(ref)
  float* bcs  = (float*)(sm+63552);        // [64] beta

  const int blk = blockIdx.x;
  const int h   = blk >> 7;
  const int icg = blk & 127;
  const int cid = blk;
  const int t   = threadIdx.x;
  const int l   = t & 63;
  const int wv  = t >> 6;
  const int lane16 = l & 15, quad = l >> 4;
  const size_t base = (size_t)(icg*CHK)*C2 + h*HD;

  // diag cell decode: block ci_b, cell (ci,cjj) with ci>=cjj (136 cells/block,
  // 128 threads/block -> threads ck<8 also own cell B = (15, 8+ck))
  const int ci_b = t >> 7;
  const int ck   = t & 127;
  int ci, cjj;
  {
    float fi = (sqrtf(8.f*(float)ck + 1.f) - 1.f)*0.5f;
    ci = (int)fi;
    cjj = ck - ((ci*(ci+1))>>1);
    if (cjj < 0){ ci--; cjj = ck - ((ci*(ci+1))>>1); }
    if (cjj > ci){ ci++; cjj = ck - ((ci*(ci+1))>>1); }
  }
  const int hasB = (ck < 8);
  const int bjB  = 8 + ck;                 // cell B = (15, bjB)

  // ---- load k,q tiles + beta
  #pragma unroll
  for (int it=0; it<2; ++it){
    int e = t + 512*it;                    // 0..1023
    int r = e >> 4, c8 = (e & 15)*8;
    *(float4*)&kT[r*136 + c8] = *(const float4*)(P_KB + base + (size_t)r*C2 + c8);
    *(float4*)&qT[r*136 + c8] = *(const float4*)(P_QB + base + (size_t)r*C2 + c8);
  }
  if (t < 64) bcs[t] = G_beta[(size_t)(icg*CHK + t)*NHD + h];

  float aaA=0.f, qqA=0.f, aaB=0.f, qqB=0.f;

  // ---- 4 quarter-d passes
  #pragma unroll 1
  for (int p=0; p<4; ++p){
    const int dq0 = p*32;
    __syncthreads();                       // gH region reusable / tiles ready
    { int r = t >> 3, f4 = (t & 7)*4;
      float4 f = *(const float4*)(G_g + base + (size_t)r*C2 + dq0 + f4);
      gH[r*38 + f4+0] = f.x; gH[r*38 + f4+1] = f.y;
      gH[r*38 + f4+2] = f.z; gH[r*38 + f4+3] = f.w;
    }
    __syncthreads();                       // gH ready
    if (t < 128){                          // ref rows 0,16,32,48
      int I = t >> 5, dd = t & 31;
      float rv = gH[(I*16)*38 + dd];
      rS[I*132 + dq0 + dd] = rv;
      er[I*132 + dq0 + dd] = expn(rv);
    }
    if (t < 32) G_egl[(size_t)cid*HD + dq0 + t] = expn(gH[63*38 + t]);
    // diag accumulation (regs)
    {
      const int rI = 16*ci_b + ci, rJ = 16*ci_b + cjj;
      const float* gRi = &gH[rI*38];
      const float* gRj = &gH[rJ*38];
      const bf16*  kRi = &kT[rI*136 + dq0];
      const bf16*  kRj = &kT[rJ*136 + dq0];
      const bf16*  qRi = &qT[rI*136 + dq0];
      float aa = aaA, qq = qqA;
      #pragma unroll 4
      for (int dd=0; dd<32; ++dd){
        float e  = expn(gRi[dd] - gRj[dd]);
        float tk = e * b2f(kRj[dd]);
        aa += tk * b2f(kRi[dd]);
        qq += tk * b2f(qRi[dd]);
      }
      aaA = aa; qqA = qq;
      if (hasB){
        const int rB = 16*ci_b + 15, rJ2 = 16*ci_b + bjB;
        const float* gRi2 = &gH[rB*38];
        const float* gRj2 = &gH[rJ2*38];
        const bf16*  kRi2 = &kT[rB*136 + dq0];
        const bf16*  kRj2 = &kT[rJ2*136 + dq0];
        const bf16*  qRi2 = &qT[rB*136 + dq0];
        float aa2 = aaB, qq2 = qqB;
        #pragma unroll 4
        for (int dd=0; dd<32; ++dd){
          float e  = expn(gRi2[dd] - gRj2[dd]);
          float tk = e * b2f(kRj2[dd]);
          aa2 += tk * b2f(kRi2[dd]);
          qq2 += tk * b2f(qRi2[dd]);
        }
        aaB = aa2; qqB = qq2;
      }
    }
    // cJ build (rows 0..47): k * e^{r_{J+1} - g}
    #pragma unroll
    for (int it=0; it<3; ++it){
      int e = t + 512*it;                  // 0..1535
      int r = e >> 5, dd = e & 31;
      float rv = gH[(((r>>4)+1)*16)*38 + dd];
      float v = b2f(kT[r*136 + dq0 + dd]) * expn(rv - gH[r*38 + dd]);
      cJ[r*136 + dq0 + dd] = f2b(v);
    }
    // ktt: k * e^{gl - g}, transposed store to global [d][r]
    {
      int d = t >> 4, r4 = (t & 15)*4;
      float gl = gH[63*38 + d];
      __attribute__((aligned(8))) bf16 tmp[4];
      #pragma unroll
      for (int u=0; u<4; ++u){
        int r = r4 + u;
        tmp[u] = f2b(b2f(kT[r*136 + dq0 + d]) * expn(gl - gH[r*38 + d]));
      }
      *(float2*)(P_KTT + (size_t)cid*(CHK*HD) + (size_t)(dq0 + d)*64 + r4) =
          *(const float2*)tmp;
    }
    __syncthreads();                       // all raw reads of quarter done
    // in-place aK/aQ + qg
    #pragma unroll
    for (int it=0; it<4; ++it){
      int e = t + 512*it;                  // 0..2047
      int r = e >> 5, dd = e & 31;
      int I = r >> 4;
      float eD  = expn(gH[r*38 + dd] - gH[(I*16)*38 + dd]);
      float erv = er[I*132 + dq0 + dd];
      int idx = r*136 + dq0 + dd;
      float av = b2f(kT[idx]) * eD;
      kT[idx] = f2b(av);
      float qv = QSCALE * b2f(qT[idx]) * eD;
      qT[idx] = f2b(qv);
      P_QG[base + (size_t)r*C2 + dq0 + dd] = f2b(qv * erv);
    }
  }
  __syncthreads();                         // aK/aQ/cJ complete

  // ---- P1: attn off-diag MFMA + diag stores + upper zeros
  short8 bfr[4];
  int pI = 0, pJ = 0;
  {
    const int PI_[6] = {1,2,2,3,3,3};
    const int PJ_[6] = {0,0,1,0,1,2};
    if (wv < 6){
      pI = PI_[wv]; pJ = PJ_[wv];
      #pragma unroll
      for (int ks=0; ks<4; ++ks){
        int k0 = ks*32 + quad*8;
        short8 raw = *(const short8*)&cJ[(16*pJ + lane16)*136 + k0];
        short8 o;
        #pragma unroll
        for (int u=0; u<8; ++u){
          int d = k0 + u;
          float m = expn(rS[pI*132 + d] - rS[(pJ+1)*132 + d]);
          o[u] = bts(s2f(raw[u]) * m);
        }
        bfr[ks] = o;
      }
      f32x4 acc;
      #pragma unroll
      for (int v=0; v<4; ++v) acc[v] = 0.f;
      #pragma unroll
      for (int ks=0; ks<4; ++ks){
        short8 af = *(const short8*)&qT[(16*pI + lane16)*136 + ks*32 + quad*8];
        acc = __builtin_amdgcn_mfma_f32_16x16x32_bf16(af, bfr[ks], acc, 0,0,0);
      }
      #pragma unroll
      for (int v=0; v<4; ++v){
        int row = 16*pI + quad*4 + v, col = 16*pJ + lane16;
        P_ATTN[(size_t)cid*4096 + row*64 + col] = f2b(acc[v]);
      }
    } else {
      const int UI_[6] = {0,0,0,1,1,2};
      const int UJ_[6] = {1,2,3,2,3,3};
      float4 zf; zf.x = zf.y = zf.z = zf.w = 0.f;
      int tt = t - 384;
      for (int e = tt; e < 192; e += 128){
        int b = e >> 5, row = (e>>1)&15, hf = e&1;
        *(float4*)(P_ATTN + (size_t)cid*4096 +
                   (size_t)((16*UI_[b]+row)*64 + 16*UJ_[b] + hf*8)) = zf;
      }
    }
    // diag qq stores + mirrored zeros
    size_t ab = (size_t)cid*4096;
    int rA = 16*ci_b + ci, cA = 16*ci_b + cjj;
    P_ATTN[ab + rA*64 + cA] = f2b(qqA * QSCALE);
    if (ci != cjj) P_ATTN[ab + cA*64 + rA] = f2b(0.f);
    if (hasB){
      int rB = 16*ci_b + 15, cB = 16*ci_b + bjB;
      P_ATTN[ab + rB*64 + cB] = f2b(qqB * QSCALE);
      if (bjB != 15) P_ATTN[ab + cB*64 + rB] = f2b(0.f);
    }
  }
  __syncthreads();                         // aQ dead; qT region -> AmD/AmL

  // ---- P2a: Gram off-diag MFMA -> AmL ; diag -> AmD
  if (wv < 6){
    f32x4 acc;
    #pragma unroll
    for (int v=0; v<4; ++v) acc[v] = 0.f;
    #pragma unroll
    for (int ks=0; ks<4; ++ks){
      short8 af = *(const short8*)&kT[(16*pI + lane16)*136 + ks*32 + quad*8];
      acc = __builtin_amdgcn_mfma_f32_16x16x32_bf16(af, bfr[ks], acc, 0,0,0);
    }
    #pragma unroll
    for (int v=0; v<4; ++v){
      int r16 = quad*4 + v;
      AmL[wv*272 + r16*17 + lane16] = acc[v] * bcs[16*pI + r16];
    }
  }
  if (ci != cjj) AmD[ci_b*272 + ci*17 + cjj] = aaA * bcs[16*ci_b + ci];
  if (hasB && bjB != 15) AmD[ci_b*272 + 15*17 + bjB] = aaB * bcs[16*ci_b + 15];
  __syncthreads();                         // AmD/AmL complete; gH -> Dinv

  // ---- P2b: invert the 4 unit-lower diag blocks (one 64-lane serial pass)
  if (wv == 0){
    const int b = l >> 4, col = l & 15;
    const float* Ab = &AmD[b*272];
    float x[16];
    #pragma unroll
    for (int i=0; i<16; ++i){
      float a = (i == col) ? 1.f : 0.f;
      #pragma unroll
      for (int kk=0; kk<i; ++kk)
        a -= Ab[i*17 + kk] * x[kk];
      x[i] = a;
      Dinv[b*272 + i*17 + col] = a;
    }
  }

  // ---- solves: inst 0,1 = u (col halves); 2,3 = w
  #pragma unroll 1
  for (int inst=0; inst<4; ++inst){
    const int isW = inst >> 1;
    const int c0  = (inst & 1) * 64;
    __syncthreads();                       // rhs free + Dinv visible
    { // build rhs
      const int r = t >> 3, c8 = (t & 7)*8;
      const float bcv = bcs[r];
      if (!isW){
        float4 f = *(const float4*)(P_VB + base + (size_t)r*C2 + c0 + c8);
        const bf16* e8 = (const bf16*)&f;
        #pragma unroll
        for (int u=0; u<8; ++u) rhs[r*66 + c8 + u] = b2f(e8[u]) * bcv;
      } else {
        const int I = r >> 4;
        #pragma unroll
        for (int u=0; u<8; ++u){
          int d = c0 + c8 + u;
          rhs[r*66 + c8 + u] = b2f(kT[r*136 + d]) * er[I*132 + d] * bcv;
        }
      }
    }
    __syncthreads();
    #pragma unroll 1
    for (int I=0; I<4; ++I){
      if (I > 0){
        #pragma unroll
        for (int e2=0; e2<2; ++e2){
          int slot = t + 512*e2;
          int r16 = slot >> 6, c = slot & 63;
          float a = rhs[(16*I + r16)*66 + c];
          #pragma unroll 1
          for (int J=0; J<I; ++J){
            const float* Arow = &AmL[(J + ((I*(I-1))>>1))*272 + r16*17];
            #pragma unroll
            for (int kk=0; kk<16; ++kk)
              a -= Arow[kk] * rhs[(16*J + kk)*66 + c];
          }
          rhs[(16*I + r16)*66 + c] = a;
        }
        __syncthreads();
      }
      float accv[2];
      #pragma unroll
      for (int e2=0; e2<2; ++e2){
        int slot = t + 512*e2;
        int r16 = slot >> 6, c = slot & 63;
        const float* Drow = &Dinv[I*272 + r16*17];
        float a = 0.f;
        #pragma unroll
        for (int kk=0; kk<16; ++kk)
          a += Drow[kk] * rhs[(16*I + kk)*66 + c];
        accv[e2] = a;
      }
      __syncthreads();
      #pragma unroll
      for (int e2=0; e2<2; ++e2){
        int slot = t + 512*e2;
        rhs[(16*I + (slot>>6))*66 + (slot & 63)] = accv[e2];
      }
      __syncthreads();
    }
    { // write out
      const int r = t >> 3, c8 = (t & 7)*8;
      __attribute__((aligned(16))) bf16 tmp[8];
      #pragma unroll
      for (int u=0; u<8; ++u) tmp[u] = f2b(rhs[r*66 + c8 + u]);
      bf16* dst = isW ? P_QB : P_VB;
      *(float4*)(dst + base + (size_t)r*C2 + c0 + c8) = *(const float4*)tmp;
    }
  }
}

// ---------------------------------------------------------------------------
// Stage 2 (MFMA): grid 256 (batch*128 + h*8 + sl), 256 thr = 4 waves.
// Per chunk: T=w@S; vn=u-T; o=ash@vn+qg@S; S=diag(egl)S+kt^T@vn.
// S master f32 in LDS [c][d]; operands bf16.
// ---------------------------------------------------------------------------
__global__ void __launch_bounds__(256) stage2_k()
{
  __shared__ float Sf[SW][HD+4];         // [c][d]
  __shared__ bf16  wqL[CHK][HD+8];       // w, then qg
  __shared__ bf16  ktL[HD][CHK+8];       // [d][j]
  __shared__ bf16  ashL[CHK][CHK+8];
  __shared__ bf16  vnT[SW][CHK+8];       // [c][j]
  __shared__ bf16  uL[CHK][SW+4];        // [j][c]
  __shared__ float egl[HD];

  const int blk = blockIdx.x;
  const int batch = blk >> 7;
  const int h  = (blk >> 3) & 15;
  const int sl = blk & 7;
  const int c0 = sl*SW;
  const int t  = threadIdx.x;
  const int l  = t & 63;
  const int wv = t >> 6;
  const int lane16 = l & 15, quad = l >> 4;
  const int R = wv*16;                   // wave row-tile

  for (int i=t;i<SW*(HD+4);i+=256) ((float*)Sf)[i] = 0.f;

  for (int ic=0; ic<NCPB; ic++){
    const int icg = batch*NCPB + ic;
    const int cid = h*128 + icg;
    const size_t rbase = (size_t)(icg*CHK)*C2 + h*HD;

    // ---- L1: stage chunk data
    float4 qgr[4];
    #pragma unroll
    for (int it=0; it<4; ++it){
      int e = (t + 256*it)*8;
      int r = e >> 7, d = e & 127;
      *(float4*)&wqL[r][d] = *(const float4*)(P_QB + rbase + (size_t)r*C2 + d);
      qgr[it] = *(const float4*)(P_QG + rbase + (size_t)r*C2 + d);
    }
    {
      const bf16* src = P_KTT + (size_t)cid*(CHK*HD);
      #pragma unroll
      for (int it=0; it<4; ++it){
        int e = (t + 256*it)*8;
        int d = e >> 6, r = e & 63;
        *(float4*)&ktL[d][r] = *(const float4*)(src + e);
      }
      const bf16* asrc = P_ATTN + (size_t)cid*(CHK*CHK);
      #pragma unroll
      for (int it=0; it<2; ++it){
        int e = (t + 256*it)*8;
        int i2 = e >> 6, j2 = e & 63;
        *(float4*)&ashL[i2][j2] = *(const float4*)(asrc + e);
      }
      int r = t>>2, c = (t&3)*4;
      const bf16* us = P_VB + rbase + (size_t)r*C2 + c0 + c;
      uL[r][c]=us[0]; uL[r][c+1]=us[1]; uL[r][c+2]=us[2]; uL[r][c+3]=us[3];
      if (t < HD) egl[t] = G_egl[(size_t)cid*HD + t];
    }
    __syncthreads();   // B0

    // ---- C1: T = w @ S ; vn = u - T
    {
      f32x4 acc1;
      #pragma unroll
      for (int v=0;v<4;v++) acc1[v]=0.f;
      #pragma unroll
      for (int ks=0; ks<4; ++ks){
        const int k0 = ks*32;
        short8 af = *(const short8*)&wqL[R+lane16][k0 + quad*8];
        short8 bfr;
        #pragma unroll
        for (int j2=0;j2<8;j2++) bfr[j2] = bts(Sf[lane16][k0 + quad*8 + j2]);
        acc1 = __builtin_amdgcn_mfma_f32_16x16x32_bf16(af, bfr, acc1, 0,0,0);
      }
      #pragma unroll
      for (int v=0;v<4;v++){
        int j = R + quad*4 + v;
        float x = b2f(uL[j][lane16]) - acc1[v];
        vnT[lane16][j] = f2b(x);
      }
    }
    __syncthreads();   // B1: vnT ready; wqL reads done

    // ---- L2: qg into wqL
    #pragma unroll
    for (int it=0; it<4; ++it){
      int e = (t + 256*it)*8;
      int r = e >> 7, d = e & 127;
      *(float4*)&wqL[r][d] = qgr[it];
    }
    __syncthreads();   // B2

    // ---- C2: o = ash@vn + qg@S
    {
      f32x4 acc2;
      #pragma unroll
      for (int v=0;v<4;v++) acc2[v]=0.f;
      #pragma unroll
      for (int ks=0; ks<2; ++ks){
        const int k0 = ks*32;
        short8 af = *(const short8*)&ashL[R+lane16][k0 + quad*8];
        short8 bfr = *(const short8*)&vnT[lane16][k0 + quad*8];
        acc2 = __builtin_amdgcn_mfma_f32_16x16x32_bf16(af, bfr, acc2, 0,0,0);
      }
      #pragma unroll
      for (int ks=0; ks<4; ++ks){
        const int k0 = ks*32;
        short8 af = *(const short8*)&wqL[R+lane16][k0 + quad*8];
        short8 bfr;
        #pragma unroll
        for (int j2=0;j2<8;j2++) bfr[j2] = bts(Sf[lane16][k0 + quad*8 + j2]);
        acc2 = __builtin_amdgcn_mfma_f32_16x16x32_bf16(af, bfr, acc2, 0,0,0);
      }
      #pragma unroll
      for (int v=0;v<4;v++){
        size_t row = (size_t)(icg*CHK) + R + quad*4 + v;
        P_CORE[row*C2 + h*HD + c0 + lane16] = f2b(acc2[v]);
      }
    }
    // ---- C3: S update
    {
      f32x4 accS[2];
      #pragma unroll
      for (int p=0;p<2;p++)
        #pragma unroll
        for (int v=0;v<4;v++) accS[p][v]=0.f;
      #pragma unroll
      for (int p=0;p<2;p++){
        const int dt = wv*2 + p;
        #pragma unroll
        for (int ks=0; ks<2; ++ks){
          const int k0 = ks*32;
          short8 af = *(const short8*)&ktL[dt*16 + lane16][k0 + quad*8];
          short8 bfr = *(const short8*)&vnT[lane16][k0 + quad*8];
          accS[p] = __builtin_amdgcn_mfma_f32_16x16x32_bf16(af, bfr, accS[p], 0,0,0);
        }
      }
      __syncthreads();  // B3: all Sf reads done
      #pragma unroll
      for (int p=0;p<2;p++){
        #pragma unroll
        for (int v=0;v<4;v++){
          int d = (wv*2+p)*16 + quad*4 + v;
          Sf[lane16][d] = Sf[lane16][d]*egl[d] + accS[p][v];
        }
      }
    }
  }
}

// RMSNorm + rms_scale + sigmoid(gate): core,gate -> opre. Grid TOT.
__global__ void __launch_bounds__(256) rms_gate_k(const float* __restrict__ rms)
{
  __shared__ float part[256];
  __shared__ float scal[16];
  const int t = threadIdx.x;
  const size_t tok = blockIdx.x;
  const int c0 = t*8;
  float v[8];
  const bf16* cr = P_CORE + tok*C2 + c0;
  #pragma unroll
  for (int u=0;u<8;u++) v[u] = b2f(cr[u]);
  float ss=0.f;
  #pragma unroll
  for (int u=0;u<8;u++) ss += v[u]*v[u];
  part[t]=ss; __syncthreads();
  if (t<16){
    float s2=0.f;
    for (int i=0;i<16;i++) s2 += part[t*16+i];
    scal[t] = rsqrtf(s2*(1.f/HD) + 1e-5f);
  }
  __syncthreads();
  float sc = scal[t>>4];
  const bf16* gr = P_GATE + tok*C2 + c0;
  bf16* orow = P_OPRE + tok*C2 + c0;
  #pragma unroll
  for (int u=0;u<8;u++){
    int d = (c0+u)&127;
    float gv = b2f(gr[u]);
    float x = v[u]*sc*rms[d];
    x *= 1.f/(1.f+__expf(-gv));
    orow[u] = f2b(x);
  }
}

// ---------------------------------------------------------------------------
extern "C" void kernel_launch(void* const* d_in, const int* in_sizes, int n_in,
                              void* d_out, int out_size, void* d_ws, size_t ws_size,
                              hipStream_t stream)
{
  const float* x     = (const float*)d_in[0];
  const float* Wq    = (const float*)d_in[1];
  const float* Wk    = (const float*)d_in[2];
  const float* Wv    = (const float*)d_in[3];
  const float* convq = (const float*)d_in[4];
  const float* convk = (const float*)d_in[5];
  const float* convv = (const float*)d_in[6];
  const float* Wb    = (const float*)d_in[7];
  const float* Wfa   = (const float*)d_in[8];
  const float* Wfb   = (const float*)d_in[9];
  const float* Wga   = (const float*)d_in[10];
  const float* Wgb   = (const float*)d_in[11];
  const float* bgb   = (const float*)d_in[12];
  const float* A_log = (const float*)d_in[13];
  const float* dtb   = (const float*)d_in[14];
  const float* rms   = (const float*)d_in[15];
  const float* Wo    = (const float*)d_in[16];
  (void)d_ws; (void)ws_size;

  dim3 blk2(16,16);
  dim3 gW(32,32), gWs(2,32);
  dim3 gM(16, TOT/128);          // (16,64)
  dim3 gMn(1, TOT/128);          // N=128
  dim3 gThin(1, TOT/128);

  wconv_t_k<<<gW, 256, 0, stream>>>(Wq, 0, C2);
  wconv_t_k<<<gW, 256, 0, stream>>>(Wk, 1, C2);
  wconv_t_k<<<gW, 256, 0, stream>>>(Wv, 2, C2);
  wconv_t_k<<<gW, 256, 0, stream>>>(Wo, 3, C2);
  wconv_t_k<<<gWs, 256, 0, stream>>>(Wga, 4, HD);

  xconv_k<<<TOT*C2/(256*8), 256, 0, stream>>>(x);

  gemm_mfma<0><<<gM, 256, 0, stream>>>(0, 0, 0, nullptr, C2);
  gemm_mfma<0><<<gM, 256, 0, stream>>>(0, 1, 1, nullptr, C2);
  gemm_mfma<0><<<gM, 256, 0, stream>>>(0, 2, 2, nullptr, C2);
  gemm_mfma<0><<<gMn, 256, 0, stream>>>(0, 4, 3, nullptr, HD);   // ga

  gemm_k<float,0,1><<<gThin, blk2, 0, stream>>>(x, -1, Wb,  nullptr, 0, TOT, NHD, C2);
  gemm_k<float,0,0><<<gThin, blk2, 0, stream>>>(x, -1, Wfa, nullptr, 1, TOT, HD,  C2);

  conv_silu_k<<<TOT, 256, 0, stream>>>(0, convq, 1);
  conv_silu_k<<<TOT, 256, 0, stream>>>(1, convk, 1);
  conv_silu_k<<<TOT, 256, 0, stream>>>(2, convv, 0);

  gemm_k<float,0,0><<<gM, blk2, 0, stream>>>((const float*)nullptr, 0, Wfb, dtb, 2, TOT, C2, HD);
  g_transform_k<<<(TOT*C2)/256, 256, 0, stream>>>(A_log);
  gcum_k<<<2048, 128, 0, stream>>>();

  stage1_k<<<2048, 512, 0, stream>>>();
  stage2_k<<<256, 256, 0, stream>>>();

  gemm_k<bf16,1,0><<<gM, blk2, 0, stream>>>((const bf16*)nullptr, 1, Wgb, bgb, 3, TOT, C2, HD);
  rms_gate_k<<<TOT, 256, 0, stream>>>(rms);

  gemm_mfma<1><<<gM, 256, 0, stream>>>(1, 3, -1, (float*)d_out, C2);
}

// Round 2
// 1575.414 us; speedup vs baseline: 1.8444x; 1.4899x over previous
//
#include <hip/hip_runtime.h>
#include <hip/hip_bf16.h>

typedef __hip_bfloat16 bf16;
typedef __attribute__((ext_vector_type(4))) float f32x4;
typedef __attribute__((ext_vector_type(8))) short short8;

#define TOT   8192      // B*S (single pass)
#define SEQ   4096
#define NHD   16
#define HD    128
#define C2    2048
#define CHK   64
#define NCPB  64        // chunks per (batch,head)
#define SW    16        // dv slice width in stage2
#define QSCALE 0.08838834764831845f

__device__ __forceinline__ float b2f(bf16 x){ return __bfloat162float(x); }
__device__ __forceinline__ bf16  f2b(float x){ return __float2bfloat16(x); }
__device__ __forceinline__ float expn(float x){ return __expf(fminf(x, 0.f)); }
__device__ __forceinline__ short bts(float x){
  bf16 b = f2b(x); short s; __builtin_memcpy(&s, &b, 2); return s;
}
__device__ __forceinline__ float s2f(short v){
  unsigned int u = ((unsigned int)(unsigned short)v) << 16;
  float f; __builtin_memcpy(&f, &u, 4); return f;
}

// ---------------------------------------------------------------------------
// Device-global scratch
// ---------------------------------------------------------------------------
__device__ __attribute__((aligned(16))) unsigned short G_xb  [TOT*C2];
__device__ __attribute__((aligned(16))) unsigned short G_xlo [TOT*C2];
__device__ __attribute__((aligned(16))) unsigned short G_qlin[TOT*C2];
__device__ __attribute__((aligned(16))) unsigned short G_klin[TOT*C2];
__device__ __attribute__((aligned(16))) unsigned short G_vlin[TOT*C2];
__device__ __attribute__((aligned(16))) unsigned short G_qb  [TOT*C2];
__device__ __attribute__((aligned(16))) unsigned short G_kb  [TOT*C2];
__device__ __attribute__((aligned(16))) unsigned short G_vb  [TOT*C2];
__device__ __attribute__((aligned(16))) unsigned short G_qg  [TOT*C2];
__device__ __attribute__((aligned(16))) unsigned short G_gate[TOT*C2];
__device__ __attribute__((aligned(16))) unsigned short G_core[TOT*C2];
__device__ __attribute__((aligned(16))) unsigned short G_opre[TOT*C2];
__device__ __attribute__((aligned(16))) float          G_g   [TOT*C2];
__device__ __attribute__((aligned(16))) unsigned short G_attn[2048*CHK*CHK];
__device__ __attribute__((aligned(16))) unsigned short G_ktt [2048*CHK*HD];
__device__ __attribute__((aligned(16))) float          G_egl [2048*HD];
__device__ __attribute__((aligned(16))) float          G_beta[TOT*NHD];
__device__ __attribute__((aligned(16))) unsigned short G_fah [TOT*HD];
__device__ __attribute__((aligned(16))) unsigned short G_fal [TOT*HD];
__device__ __attribute__((aligned(16))) unsigned short G_ga  [TOT*HD];
__device__ __attribute__((aligned(16))) unsigned short G_Wqt [C2*C2];
__device__ __attribute__((aligned(16))) unsigned short G_Wkt [C2*C2];
__device__ __attribute__((aligned(16))) unsigned short G_Wvt [C2*C2];
__device__ __attribute__((aligned(16))) unsigned short G_Wot [C2*C2];
__device__ __attribute__((aligned(16))) unsigned short G_Wgat  [HD*C2];
__device__ __attribute__((aligned(16))) unsigned short G_Wbt   [16*C2];
__device__ __attribute__((aligned(16))) unsigned short G_Wfat_h[HD*C2];
__device__ __attribute__((aligned(16))) unsigned short G_Wfat_l[HD*C2];
__device__ __attribute__((aligned(16))) unsigned short G_Wfbt_h[C2*HD];
__device__ __attribute__((aligned(16))) unsigned short G_Wfbt_l[C2*HD];
__device__ __attribute__((aligned(16))) unsigned short G_Wgbt  [C2*HD];

#define P_QLIN ((bf16*)G_qlin)
#define P_KLIN ((bf16*)G_klin)
#define P_VLIN ((bf16*)G_vlin)
#define P_QB   ((bf16*)G_qb)
#define P_KB   ((bf16*)G_kb)
#define P_VB   ((bf16*)G_vb)
#define P_QG   ((bf16*)G_qg)
#define P_GATE ((bf16*)G_gate)
#define P_CORE ((bf16*)G_core)
#define P_OPRE ((bf16*)G_opre)
#define P_ATTN ((bf16*)G_attn)
#define P_KTT  ((bf16*)G_ktt)
#define P_FAH  ((bf16*)G_fah)
#define P_FAL  ((bf16*)G_fal)
#define P_GA   ((bf16*)G_ga)

__device__ __forceinline__ const bf16* selWt(int s){
  switch(s){ case 0: return (const bf16*)G_Wqt; case 1: return (const bf16*)G_Wkt;
             case 2: return (const bf16*)G_Wvt; }
  return (const bf16*)G_Wot;
}
__device__ __forceinline__ bf16* selCm(int s){
  switch(s){ case 0: return P_QLIN; case 1: return P_KLIN; }
  return P_VLIN;
}
__device__ __forceinline__ bf16* selWT(int s){
  switch(s){
    case 0: return (bf16*)G_Wqt;     case 1: return (bf16*)G_Wkt;
    case 2: return (bf16*)G_Wvt;     case 3: return (bf16*)G_Wot;
    case 4: return (bf16*)G_Wgat;    case 5: return (bf16*)G_Wbt;
    case 6: return (bf16*)G_Wfat_h;  case 7: return (bf16*)G_Wfat_l;
    case 8: return (bf16*)G_Wfbt_h;  case 9: return (bf16*)G_Wfbt_l;
  }
  return (bf16*)G_Wgbt;
}

// ---------------------------------------------------------------------------
// Weight transpose+convert: W f32 [K][N] -> Wt bf16 [N][K] (+ optional lo).
// Grid (ceil(N/64), K/64), 256 thr.
// ---------------------------------------------------------------------------
__global__ void __launch_bounds__(256) wtrans_k(const float* __restrict__ W,
                                                int selH, int selL, int N, int K)
{
  __shared__ float tile[64][65];
  const int t = threadIdx.x;
  const int n0 = blockIdx.x*64, k0 = blockIdx.y*64;
  const int c4 = (t&15)*4, rr = t>>4;
  if (n0 + c4 < N){
    #pragma unroll
    for (int i=0;i<4;i++){
      const float* src = W + (size_t)(k0+rr+16*i)*N + n0 + c4;
      float4 f = *(const float4*)src;
      tile[rr+16*i][c4+0]=f.x; tile[rr+16*i][c4+1]=f.y;
      tile[rr+16*i][c4+2]=f.z; tile[rr+16*i][c4+3]=f.w;
    }
  }
  __syncthreads();
  bf16* outH = selWT(selH);
  bf16* outL = (selL >= 0) ? selWT(selL) : nullptr;
  const int nr = t>>3, kc = (t&7)*8;
  #pragma unroll
  for (int p=0;p<2;p++){
    int n = p*32 + nr;
    if (n0 + n < N){
      __attribute__((aligned(16))) bf16 tmpH[8];
      __attribute__((aligned(16))) bf16 tmpL[8];
      #pragma unroll
      for (int j=0;j<8;j++){
        float v = tile[kc+j][n];
        bf16 hh = f2b(v);
        tmpH[j] = hh;
        tmpL[j] = f2b(v - b2f(hh));
      }
      *(float4*)(outH + (size_t)(n0+n)*K + k0 + kc) = *(const float4*)tmpH;
      if (outL)
        *(float4*)(outL + (size_t)(n0+n)*K + k0 + kc) = *(const float4*)tmpL;
    }
  }
}

// x f32 -> G_xb (hi) + G_xlo (residual) bf16
__global__ void __launch_bounds__(256) xconv_k(const float* __restrict__ x)
{
  size_t idx = ((size_t)blockIdx.x*256 + threadIdx.x)*8;
  const float* src = x + idx;
  float4 f0 = *(const float4*)src, f1 = *(const float4*)(src+4);
  float v[8] = {f0.x,f0.y,f0.z,f0.w,f1.x,f1.y,f1.z,f1.w};
  __attribute__((aligned(16))) bf16 th[8];
  __attribute__((aligned(16))) bf16 tl[8];
  #pragma unroll
  for (int u=0;u<8;u++){
    bf16 h = f2b(v[u]);
    th[u] = h;
    tl[u] = f2b(v[u] - b2f(h));
  }
  *(float4*)((bf16*)G_xb  + idx) = *(const float4*)th;
  *(float4*)((bf16*)G_xlo + idx) = *(const float4*)tl;
}

// ---------------------------------------------------------------------------
// MFMA GEMM: C[M,N] = A[M,K=2048] @ Bt[N,K]^T, bf16 in, f32 acc.
// 128x128 tile, BK=32, 4 waves x (64x64).
// outMode 0: bf16 -> selCm(cSel), stride N.  outMode 1: f32 -> Cw, stride N.
// ---------------------------------------------------------------------------
template<int OUTMODE>
__global__ void __launch_bounds__(256) gemm_mfma(
    int aSel, int bSel, int cSel, float* __restrict__ Cw, int N)
{
  const bf16* A  = (aSel==0) ? (const bf16*)G_xb : (const bf16*)G_opre;
  const bf16* Bt = selWt(bSel);
  __shared__ bf16 As[128*40];
  __shared__ bf16 Bs[128*40];
  const int t  = threadIdx.x;
  const int l  = t & 63;
  const int wv = t >> 6;
  const int wm = (wv>>1)*64, wn = (wv&1)*64;
  const int bm = blockIdx.y*128, bn = blockIdx.x*128;
  const int lr = l & 15;
  const int lk = (l>>4)*8;
  const int sr = t>>1, sc = (t&1)*16;

  f32x4 acc[4][4];
  #pragma unroll
  for (int i=0;i<4;i++)
    #pragma unroll
    for (int j=0;j<4;j++)
      #pragma unroll
      for (int v=0;v<4;v++) acc[i][j][v] = 0.f;

  for (int k0=0; k0<C2; k0+=32){
    const bf16* ga = A  + (size_t)(bm+sr)*C2 + k0 + sc;
    const bf16* gb = Bt + (size_t)(bn+sr)*C2 + k0 + sc;
    float4 a0 = *(const float4*)ga; float4 a1 = *(const float4*)(ga+8);
    float4 b0 = *(const float4*)gb; float4 b1 = *(const float4*)(gb+8);
    __syncthreads();
    *(float4*)&As[sr*40+sc]   = a0; *(float4*)&As[sr*40+sc+8] = a1;
    *(float4*)&Bs[sr*40+sc]   = b0; *(float4*)&Bs[sr*40+sc+8] = b1;
    __syncthreads();
    short8 af[4], bfr[4];
    #pragma unroll
    for (int i=0;i<4;i++){
      af[i]  = *(const short8*)&As[(wm+i*16+lr)*40 + lk];
      bfr[i] = *(const short8*)&Bs[(wn+i*16+lr)*40 + lk];
    }
    #pragma unroll
    for (int i=0;i<4;i++)
      #pragma unroll
      for (int j=0;j<4;j++)
        acc[i][j] = __builtin_amdgcn_mfma_f32_16x16x32_bf16(af[i], bfr[j], acc[i][j], 0, 0, 0);
  }

  bf16* Cb = (OUTMODE==0) ? selCm(cSel) : nullptr;
  #pragma unroll
  for (int i=0;i<4;i++){
    #pragma unroll
    for (int v=0;v<4;v++){
      int r = bm + wm + i*16 + (l>>4)*4 + v;
      #pragma unroll
      for (int j=0;j<4;j++){
        int col = bn + wn + j*16 + (l&15);
        float val = acc[i][j][v];
        if (OUTMODE==1) Cw[(size_t)r*N + col] = val;
        else            Cb[(size_t)r*N + col] = f2b(val);
      }
    }
  }
}

// ---------------------------------------------------------------------------
// Fused thin x-projections (MFMA): beta (N=16, sigmoid, f32),
// fa (N=128, split-bf16 3-pass -> hi/lo), ga (N=128, bf16).
// Grid 256 blocks (M-tile 32), 256 thr = 4 waves: rb = wv>>1, nhalf = wv&1.
// ---------------------------------------------------------------------------
__global__ void __launch_bounds__(256) thinx_k()
{
  const int t = threadIdx.x;
  const int l = t & 63;
  const int wv = t >> 6;
  const int rb = wv >> 1, nh = wv & 1;
  const int lane16 = l & 15, quad = l >> 4;
  const int bm = blockIdx.x*32;
  const int arow = bm + rb*16 + lane16;

  const bf16* Ah = (const bf16*)G_xb  + (size_t)arow*C2;
  const bf16* Al = (const bf16*)G_xlo + (size_t)arow*C2;
  const bf16* Wfh = (const bf16*)G_Wfat_h;
  const bf16* Wfl = (const bf16*)G_Wfat_l;
  const bf16* Wg  = (const bf16*)G_Wgat;
  const bf16* Wbp = (const bf16*)G_Wbt;

  f32x4 accF[4], accG[4], accB;
  #pragma unroll
  for (int cb=0;cb<4;cb++)
    #pragma unroll
    for (int v=0;v<4;v++){ accF[cb][v]=0.f; accG[cb][v]=0.f; }
  #pragma unroll
  for (int v=0;v<4;v++) accB[v]=0.f;

  for (int k0=0; k0<C2; k0+=32){
    const int ko = k0 + quad*8;
    short8 ah = *(const short8*)(Ah + ko);
    short8 al = *(const short8*)(Al + ko);
    #pragma unroll
    for (int cb=0;cb<4;cb++){
      const size_t nrow = (size_t)(nh*64 + cb*16 + lane16)*C2 + ko;
      short8 bh = *(const short8*)(Wfh + nrow);
      short8 bl = *(const short8*)(Wfl + nrow);
      accF[cb] = __builtin_amdgcn_mfma_f32_16x16x32_bf16(ah, bh, accF[cb], 0,0,0);
      accF[cb] = __builtin_amdgcn_mfma_f32_16x16x32_bf16(ah, bl, accF[cb], 0,0,0);
      accF[cb] = __builtin_amdgcn_mfma_f32_16x16x32_bf16(al, bh, accF[cb], 0,0,0);
      short8 bg = *(const short8*)(Wg + nrow);
      accG[cb] = __builtin_amdgcn_mfma_f32_16x16x32_bf16(ah, bg, accG[cb], 0,0,0);
    }
    if (nh == 0){
      short8 bb = *(const short8*)(Wbp + (size_t)lane16*C2 + ko);
      accB = __builtin_amdgcn_mfma_f32_16x16x32_bf16(ah, bb, accB, 0,0,0);
    }
  }

  #pragma unroll
  for (int cb=0;cb<4;cb++){
    #pragma unroll
    for (int v=0;v<4;v++){
      int r = bm + rb*16 + quad*4 + v;
      int n = nh*64 + cb*16 + lane16;
      float vf = accF[cb][v];
      bf16 fh = f2b(vf);
      P_FAH[(size_t)r*HD + n] = fh;
      P_FAL[(size_t)r*HD + n] = f2b(vf - b2f(fh));
      P_GA [(size_t)r*HD + n] = f2b(accG[cb][v]);
    }
  }
  if (nh == 0){
    #pragma unroll
    for (int v=0;v<4;v++){
      int r = bm + rb*16 + quad*4 + v;
      G_beta[(size_t)r*NHD + lane16] = 1.f/(1.f + __expf(-accB[v]));
    }
  }
}

// ---------------------------------------------------------------------------
// glin_k: G_g = fa @ Wfb + dtb (split-bf16, ~f32 precision), f32 out.
// M=8192, N=2048, K=128. Grid (16,64), 256 thr, 4 waves x (64x64).
// ---------------------------------------------------------------------------
__global__ void __launch_bounds__(256) glin_k(const float* __restrict__ dtb)
{
  const int t = threadIdx.x;
  const int l = t & 63;
  const int wv = t >> 6;
  const int wm = (wv>>1)*64, wn = (wv&1)*64;
  const int bm = blockIdx.y*128, bn = blockIdx.x*128;
  const int lane16 = l & 15, quad = l >> 4;

  f32x4 acc[4][4];
  #pragma unroll
  for (int i=0;i<4;i++)
    #pragma unroll
    for (int j=0;j<4;j++)
      #pragma unroll
      for (int v=0;v<4;v++) acc[i][j][v]=0.f;

  #pragma unroll
  for (int pass=0; pass<3; ++pass){
    const bf16* A = (pass < 2) ? P_FAH : P_FAL;
    const bf16* B = (pass == 1) ? (const bf16*)G_Wfbt_l : (const bf16*)G_Wfbt_h;
    #pragma unroll
    for (int ks=0; ks<4; ++ks){
      short8 af[4], bfr[4];
      #pragma unroll
      for (int i=0;i<4;i++)
        af[i] = *(const short8*)(A + (size_t)(bm+wm+i*16+lane16)*HD + ks*32 + quad*8);
      #pragma unroll
      for (int j=0;j<4;j++)
        bfr[j] = *(const short8*)(B + (size_t)(bn+wn+j*16+lane16)*HD + ks*32 + quad*8);
      #pragma unroll
      for (int i=0;i<4;i++)
        #pragma unroll
        for (int j=0;j<4;j++)
          acc[i][j] = __builtin_amdgcn_mfma_f32_16x16x32_bf16(af[i], bfr[j], acc[i][j], 0,0,0);
    }
  }

  #pragma unroll
  for (int i=0;i<4;i++){
    #pragma unroll
    for (int v=0;v<4;v++){
      int r = bm + wm + i*16 + quad*4 + v;
      #pragma unroll
      for (int j=0;j<4;j++){
        int n = bn + wn + j*16 + lane16;
        G_g[(size_t)r*C2 + n] = acc[i][j][v] + dtb[n];
      }
    }
  }
}

// ---------------------------------------------------------------------------
// gate_k: G_gate = ga @ Wgb + bgb (bf16). M=8192, N=2048, K=128.
// ---------------------------------------------------------------------------
__global__ void __launch_bounds__(256) gate_k(const float* __restrict__ bgb)
{
  const int t = threadIdx.x;
  const int l = t & 63;
  const int wv = t >> 6;
  const int wm = (wv>>1)*64, wn = (wv&1)*64;
  const int bm = blockIdx.y*128, bn = blockIdx.x*128;
  const int lane16 = l & 15, quad = l >> 4;

  f32x4 acc[4][4];
  #pragma unroll
  for (int i=0;i<4;i++)
    #pragma unroll
    for (int j=0;j<4;j++)
      #pragma unroll
      for (int v=0;v<4;v++) acc[i][j][v]=0.f;

  const bf16* A = P_GA;
  const bf16* B = (const bf16*)G_Wgbt;
  #pragma unroll
  for (int ks=0; ks<4; ++ks){
    short8 af[4], bfr[4];
    #pragma unroll
    for (int i=0;i<4;i++)
      af[i] = *(const short8*)(A + (size_t)(bm+wm+i*16+lane16)*HD + ks*32 + quad*8);
    #pragma unroll
    for (int j=0;j<4;j++)
      bfr[j] = *(const short8*)(B + (size_t)(bn+wn+j*16+lane16)*HD + ks*32 + quad*8);
    #pragma unroll
    for (int i=0;i<4;i++)
      #pragma unroll
      for (int j=0;j<4;j++)
        acc[i][j] = __builtin_amdgcn_mfma_f32_16x16x32_bf16(af[i], bfr[j], acc[i][j], 0,0,0);
  }

  #pragma unroll
  for (int i=0;i<4;i++){
    #pragma unroll
    for (int v=0;v<4;v++){
      int r = bm + wm + i*16 + quad*4 + v;
      #pragma unroll
      for (int j=0;j<4;j++){
        int n = bn + wn + j*16 + lane16;
        P_GATE[(size_t)r*C2 + n] = f2b(acc[i][j][v] + bgb[n]);
      }
    }
  }
}

// ---------------------------------------------------------------------------
// Causal depthwise conv (K=4) + SiLU + optional l2norm. Grid TOT.
// ---------------------------------------------------------------------------
__global__ void __launch_bounds__(256) conv_silu_k(
    int sel, const float* __restrict__ kern, int do_norm)
{
  const bf16* lin = sel==0 ? P_QLIN : sel==1 ? P_KLIN : P_VLIN;
  bf16*       out = sel==0 ? P_QB   : sel==1 ? P_KB   : P_VB;

  __shared__ float part[256];
  __shared__ float scal[16];
  const int t = threadIdx.x;
  const int r = blockIdx.x;
  const int s = r & (SEQ-1);
  const int c0 = t*8;
  float v[8];
  #pragma unroll
  for (int u=0;u<8;u++) v[u]=0.f;
  for (int j=0;j<4;j++){
    int sp = s - 3 + j;
    if (sp < 0) continue;
    const bf16* row = lin + (size_t)(r-3+j)*C2 + c0;
    const float* kr = kern + j*C2 + c0;
    #pragma unroll
    for (int u=0;u<8;u++) v[u] += b2f(row[u]) * kr[u];
  }
  #pragma unroll
  for (int u=0;u<8;u++){ float x=v[u]; v[u] = x / (1.f + __expf(-x)); }
  if (do_norm) {
    float ss=0.f;
    #pragma unroll
    for (int u=0;u<8;u++) ss += v[u]*v[u];
    part[t]=ss; __syncthreads();
    if (t<16){
      float s2=0.f;
      for (int i=0;i<16;i++) s2 += part[t*16+i];
      scal[t] = rsqrtf(s2 + 1e-6f);
    }
    __syncthreads();
    float sc = scal[t>>4];
    #pragma unroll
    for (int u=0;u<8;u++) v[u] *= sc;
  }
  bf16* orow = out + (size_t)r*C2 + c0;
  #pragma unroll
  for (int u=0;u<8;u++) orow[u] = f2b(v[u]);
}

// g = -exp(A_log[h]) * softplus(g_lin)
__global__ void __launch_bounds__(256) g_transform_k(const float* __restrict__ A_log)
{
  size_t i = (size_t)blockIdx.x*256 + threadIdx.x;
  float x = fminf(G_g[i], 80.f);
  int h = (int)((i >> 7) & (NHD-1));
  float a = __expf(A_log[h]);
  float sp = (x > 20.f) ? x : log1pf(__expf(x));
  G_g[i] = -a * sp;
}

// Per-chunk cumsum. Grid 2048 x 128.
__global__ void __launch_bounds__(128) gcum_k()
{
  const int blk = blockIdx.x;
  const int icg = blk & 127, h = blk >> 7;
  const int d = threadIdx.x;
  size_t gi = (size_t)(icg*CHK)*C2 + h*HD + d;
  float a = 0.f;
  for (int r=0;r<CHK;r++){ a += G_g[gi]; G_g[gi] = a; gi += C2; }
}

// ---------------------------------------------------------------------------
// Stage 1 (MFMA rewrite): grid 2048 (h*128+icg), 512 thr = 8 waves.
// ---------------------------------------------------------------------------
__global__ void __launch_bounds__(512, 4) stage1_k()
{
  __shared__ __attribute__((aligned(16))) char sm[63872];
  bf16*  kT   = (bf16*)sm;                 // [64][136] raw k -> aK (in place)
  bf16*  qT   = (bf16*)(sm+17408);         // [64][136] raw q -> aQ (in place)
  float* AmD  = (float*)(sm+17408);        // [4][16][17]  (post-P1, over qT)
  float* AmL  = (float*)(sm+21760);        // [6][16][17]  (post-P1, over qT)
  float* gH   = (float*)(sm+34816);        // [64][38] quarter-d g (passes)
  float* Dinv = (float*)(sm+34816);        // [4][16][17]  (post-pass, over gH)
  bf16*  cJ   = (bf16*)(sm+44544);         // [48][136] k*e^{r_{J+1}-g}
  float* rhs  = (float*)(sm+44544);        // [64][66] solve buffer (over cJ+rS)
  float* rS   = (float*)(sm+57600);        // [4][132] ref rows of g
  float* er   = (float*)(sm+61440);        // [4][132] exp(ref)
  float* bcs  = (float*)(sm+63552);        // [64] beta

  const int blk = blockIdx.x;
  const int h   = blk >> 7;
  const int icg = blk & 127;
  const int cid = blk;
  const int t   = threadIdx.x;
  const int l   = t & 63;
  const int wv  = t >> 6;
  const int lane16 = l & 15, quad = l >> 4;
  const size_t base = (size_t)(icg*CHK)*C2 + h*HD;

  const int ci_b = t >> 7;
  const int ck   = t & 127;
  int ci, cjj;
  {
    float fi = (sqrtf(8.f*(float)ck + 1.f) - 1.f)*0.5f;
    ci = (int)fi;
    cjj = ck - ((ci*(ci+1))>>1);
    if (cjj < 0){ ci--; cjj = ck - ((ci*(ci+1))>>1); }
    if (cjj > ci){ ci++; cjj = ck - ((ci*(ci+1))>>1); }
  }
  const int hasB = (ck < 8);
  const int bjB  = 8 + ck;

  #pragma unroll
  for (int it=0; it<2; ++it){
    int e = t + 512*it;
    int r = e >> 4, c8 = (e & 15)*8;
    *(float4*)&kT[r*136 + c8] = *(const float4*)(P_KB + base + (size_t)r*C2 + c8);
    *(float4*)&qT[r*136 + c8] = *(const float4*)(P_QB + base + (size_t)r*C2 + c8);
  }
  if (t < 64) bcs[t] = G_beta[(size_t)(icg*CHK + t)*NHD + h];

  float aaA=0.f, qqA=0.f, aaB=0.f, qqB=0.f;

  #pragma unroll 1
  for (int p=0; p<4; ++p){
    const int dq0 = p*32;
    __syncthreads();
    { int r = t >> 3, f4 = (t & 7)*4;
      float4 f = *(const float4*)(G_g + base + (size_t)r*C2 + dq0 + f4);
      gH[r*38 + f4+0] = f.x; gH[r*38 + f4+1] = f.y;
      gH[r*38 + f4+2] = f.z; gH[r*38 + f4+3] = f.w;
    }
    __syncthreads();
    if (t < 128){
      int I = t >> 5, dd = t & 31;
      float rv = gH[(I*16)*38 + dd];
      rS[I*132 + dq0 + dd] = rv;
      er[I*132 + dq0 + dd] = expn(rv);
    }
    if (t < 32) G_egl[(size_t)cid*HD + dq0 + t] = expn(gH[63*38 + t]);
    {
      const int rI = 16*ci_b + ci, rJ = 16*ci_b + cjj;
      const float* gRi = &gH[rI*38];
      const float* gRj = &gH[rJ*38];
      const bf16*  kRi = &kT[rI*136 + dq0];
      const bf16*  kRj = &kT[rJ*136 + dq0];
      const bf16*  qRi = &qT[rI*136 + dq0];
      float aa = aaA, qq = qqA;
      #pragma unroll 4
      for (int dd=0; dd<32; ++dd){
        float e  = expn(gRi[dd] - gRj[dd]);
        float tk = e * b2f(kRj[dd]);
        aa += tk * b2f(kRi[dd]);
        qq += tk * b2f(qRi[dd]);
      }
      aaA = aa; qqA = qq;
      if (hasB){
        const int rB = 16*ci_b + 15, rJ2 = 16*ci_b + bjB;
        const float* gRi2 = &gH[rB*38];
        const float* gRj2 = &gH[rJ2*38];
        const bf16*  kRi2 = &kT[rB*136 + dq0];
        const bf16*  kRj2 = &kT[rJ2*136 + dq0];
        const bf16*  qRi2 = &qT[rB*136 + dq0];
        float aa2 = aaB, qq2 = qqB;
        #pragma unroll 4
        for (int dd=0; dd<32; ++dd){
          float e  = expn(gRi2[dd] - gRj2[dd]);
          float tk = e * b2f(kRj2[dd]);
          aa2 += tk * b2f(kRi2[dd]);
          qq2 += tk * b2f(qRi2[dd]);
        }
        aaB = aa2; qqB = qq2;
      }
    }
    #pragma unroll
    for (int it=0; it<3; ++it){
      int e = t + 512*it;
      int r = e >> 5, dd = e & 31;
      float rv = gH[(((r>>4)+1)*16)*38 + dd];
      float v = b2f(kT[r*136 + dq0 + dd]) * expn(rv - gH[r*38 + dd]);
      cJ[r*136 + dq0 + dd] = f2b(v);
    }
    {
      int d = t >> 4, r4 = (t & 15)*4;
      float gl = gH[63*38 + d];
      __attribute__((aligned(8))) bf16 tmp[4];
      #pragma unroll
      for (int u=0; u<4; ++u){
        int r = r4 + u;
        tmp[u] = f2b(b2f(kT[r*136 + dq0 + d]) * expn(gl - gH[r*38 + d]));
      }
      *(float2*)(P_KTT + (size_t)cid*(CHK*HD) + (size_t)(dq0 + d)*64 + r4) =
          *(const float2*)tmp;
    }
    __syncthreads();
    #pragma unroll
    for (int it=0; it<4; ++it){
      int e = t + 512*it;
      int r = e >> 5, dd = e & 31;
      int I = r >> 4;
      float eD  = expn(gH[r*38 + dd] - gH[(I*16)*38 + dd]);
      float erv = er[I*132 + dq0 + dd];
      int idx = r*136 + dq0 + dd;
      float av = b2f(kT[idx]) * eD;
      kT[idx] = f2b(av);
      float qv = QSCALE * b2f(qT[idx]) * eD;
      qT[idx] = f2b(qv);
      P_QG[base + (size_t)r*C2 + dq0 + dd] = f2b(qv * erv);
    }
  }
  __syncthreads();

  short8 bfr[4];
  int pI = 0, pJ = 0;
  {
    const int PI_[6] = {1,2,2,3,3,3};
    const int PJ_[6] = {0,0,1,0,1,2};
    if (wv < 6){
      pI = PI_[wv]; pJ = PJ_[wv];
      #pragma unroll
      for (int ks=0; ks<4; ++ks){
        int k0 = ks*32 + quad*8;
        short8 raw = *(const short8*)&cJ[(16*pJ + lane16)*136 + k0];
        short8 o;
        #pragma unroll
        for (int u=0; u<8; ++u){
          int d = k0 + u;
          float m = expn(rS[pI*132 + d] - rS[(pJ+1)*132 + d]);
          o[u] = bts(s2f(raw[u]) * m);
        }
        bfr[ks] = o;
      }
      f32x4 acc;
      #pragma unroll
      for (int v=0; v<4; ++v) acc[v] = 0.f;
      #pragma unroll
      for (int ks=0; ks<4; ++ks){
        short8 af = *(const short8*)&qT[(16*pI + lane16)*136 + ks*32 + quad*8];
        acc = __builtin_amdgcn_mfma_f32_16x16x32_bf16(af, bfr[ks], acc, 0,0,0);
      }
      #pragma unroll
      for (int v=0; v<4; ++v){
        int row = 16*pI + quad*4 + v, col = 16*pJ + lane16;
        P_ATTN[(size_t)cid*4096 + row*64 + col] = f2b(acc[v]);
      }
    } else {
      const int UI_[6] = {0,0,0,1,1,2};
      const int UJ_[6] = {1,2,3,2,3,3};
      float4 zf; zf.x = zf.y = zf.z = zf.w = 0.f;
      int tt = t - 384;
      for (int e = tt; e < 192; e += 128){
        int b = e >> 5, row = (e>>1)&15, hf = e&1;
        *(float4*)(P_ATTN + (size_t)cid*4096 +
                   (size_t)((16*UI_[b]+row)*64 + 16*UJ_[b] + hf*8)) = zf;
      }
    }
    size_t ab = (size_t)cid*4096;
    int rA = 16*ci_b + ci, cA = 16*ci_b + cjj;
    P_ATTN[ab + rA*64 + cA] = f2b(qqA * QSCALE);
    if (ci != cjj) P_ATTN[ab + cA*64 + rA] = f2b(0.f);
    if (hasB){
      int rB = 16*ci_b + 15, cB = 16*ci_b + bjB;
      P_ATTN[ab + rB*64 + cB] = f2b(qqB * QSCALE);
      if (bjB != 15) P_ATTN[ab + cB*64 + rB] = f2b(0.f);
    }
  }
  __syncthreads();

  if (wv < 6){
    f32x4 acc;
    #pragma unroll
    for (int v=0; v<4; ++v) acc[v] = 0.f;
    #pragma unroll
    for (int ks=0; ks<4; ++ks){
      short8 af = *(const short8*)&kT[(16*pI + lane16)*136 + ks*32 + quad*8];
      acc = __builtin_amdgcn_mfma_f32_16x16x32_bf16(af, bfr[ks], acc, 0,0,0);
    }
    #pragma unroll
    for (int v=0; v<4; ++v){
      int r16 = quad*4 + v;
      AmL[wv*272 + r16*17 + lane16] = acc[v] * bcs[16*pI + r16];
    }
  }
  if (ci != cjj) AmD[ci_b*272 + ci*17 + cjj] = aaA * bcs[16*ci_b + ci];
  if (hasB && bjB != 15) AmD[ci_b*272 + 15*17 + bjB] = aaB * bcs[16*ci_b + 15];
  __syncthreads();

  if (wv == 0){
    const int b = l >> 4, col = l & 15;
    const float* Ab = &AmD[b*272];
    float x[16];
    #pragma unroll
    for (int i=0; i<16; ++i){
      float a = (i == col) ? 1.f : 0.f;
      #pragma unroll
      for (int kk=0; kk<i; ++kk)
        a -= Ab[i*17 + kk] * x[kk];
      x[i] = a;
      Dinv[b*272 + i*17 + col] = a;
    }
  }

  #pragma unroll 1
  for (int inst=0; inst<4; ++inst){
    const int isW = inst >> 1;
    const int c0  = (inst & 1) * 64;
    __syncthreads();
    {
      const int r = t >> 3, c8 = (t & 7)*8;
      const float bcv = bcs[r];
      if (!isW){
        float4 f = *(const float4*)(P_VB + base + (size_t)r*C2 + c0 + c8);
        const bf16* e8 = (const bf16*)&f;
        #pragma unroll
        for (int u=0; u<8; ++u) rhs[r*66 + c8 + u] = b2f(e8[u]) * bcv;
      } else {
        const int I = r >> 4;
        #pragma unroll
        for (int u=0; u<8; ++u){
          int d = c0 + c8 + u;
          rhs[r*66 + c8 + u] = b2f(kT[r*136 + d]) * er[I*132 + d] * bcv;
        }
      }
    }
    __syncthreads();
    #pragma unroll 1
    for (int I=0; I<4; ++I){
      if (I > 0){
        #pragma unroll
        for (int e2=0; e2<2; ++e2){
          int slot = t + 512*e2;
          int r16 = slot >> 6, c = slot & 63;
          float a = rhs[(16*I + r16)*66 + c];
          #pragma unroll 1
          for (int J=0; J<I; ++J){
            const float* Arow = &AmL[(J + ((I*(I-1))>>1))*272 + r16*17];
            #pragma unroll
            for (int kk=0; kk<16; ++kk)
              a -= Arow[kk] * rhs[(16*J + kk)*66 + c];
          }
          rhs[(16*I + r16)*66 + c] = a;
        }
        __syncthreads();
      }
      float accv[2];
      #pragma unroll
      for (int e2=0; e2<2; ++e2){
        int slot = t + 512*e2;
        int r16 = slot >> 6, c = slot & 63;
        const float* Drow = &Dinv[I*272 + r16*17];
        float a = 0.f;
        #pragma unroll
        for (int kk=0; kk<16; ++kk)
          a += Drow[kk] * rhs[(16*I + kk)*66 + c];
        accv[e2] = a;
      }
      __syncthreads();
      #pragma unroll
      for (int e2=0; e2<2; ++e2){
        int slot = t + 512*e2;
        rhs[(16*I + (slot>>6))*66 + (slot & 63)] = accv[e2];
      }
      __syncthreads();
    }
    {
      const int r = t >> 3, c8 = (t & 7)*8;
      __attribute__((aligned(16))) bf16 tmp[8];
      #pragma unroll
      for (int u=0; u<8; ++u) tmp[u] = f2b(rhs[r*66 + c8 + u]);
      bf16* dst = isW ? P_QB : P_VB;
      *(float4*)(dst + base + (size_t)r*C2 + c0 + c8) = *(const float4*)tmp;
    }
  }
}

// ---------------------------------------------------------------------------
// Stage 2 (MFMA): grid 256 (batch*128 + h*8 + sl), 256 thr = 4 waves.
// ---------------------------------------------------------------------------
__global__ void __launch_bounds__(256) stage2_k()
{
  __shared__ float Sf[SW][HD+4];
  __shared__ bf16  wqL[CHK][HD+8];
  __shared__ bf16  ktL[HD][CHK+8];
  __shared__ bf16  ashL[CHK][CHK+8];
  __shared__ bf16  vnT[SW][CHK+8];
  __shared__ bf16  uL[CHK][SW+4];
  __shared__ float egl[HD];

  const int blk = blockIdx.x;
  const int batch = blk >> 7;
  const int h  = (blk >> 3) & 15;
  const int sl = blk & 7;
  const int c0 = sl*SW;
  const int t  = threadIdx.x;
  const int l  = t & 63;
  const int wv = t >> 6;
  const int lane16 = l & 15, quad = l >> 4;
  const int R = wv*16;

  for (int i=t;i<SW*(HD+4);i+=256) ((float*)Sf)[i] = 0.f;

  for (int ic=0; ic<NCPB; ic++){
    const int icg = batch*NCPB + ic;
    const int cid = h*128 + icg;
    const size_t rbase = (size_t)(icg*CHK)*C2 + h*HD;

    float4 qgr[4];
    #pragma unroll
    for (int it=0; it<4; ++it){
      int e = (t + 256*it)*8;
      int r = e >> 7, d = e & 127;
      *(float4*)&wqL[r][d] = *(const float4*)(P_QB + rbase + (size_t)r*C2 + d);
      qgr[it] = *(const float4*)(P_QG + rbase + (size_t)r*C2 + d);
    }
    {
      const bf16* src = P_KTT + (size_t)cid*(CHK*HD);
      #pragma unroll
      for (int it=0; it<4; ++it){
        int e = (t + 256*it)*8;
        int d = e >> 6, r = e & 63;
        *(float4*)&ktL[d][r] = *(const float4*)(src + e);
      }
      const bf16* asrc = P_ATTN + (size_t)cid*(CHK*CHK);
      #pragma unroll
      for (int it=0; it<2; ++it){
        int e = (t + 256*it)*8;
        int i2 = e >> 6, j2 = e & 63;
        *(float4*)&ashL[i2][j2] = *(const float4*)(asrc + e);
      }
      int r = t>>2, c = (t&3)*4;
      const bf16* us = P_VB + rbase + (size_t)r*C2 + c0 + c;
      uL[r][c]=us[0]; uL[r][c+1]=us[1]; uL[r][c+2]=us[2]; uL[r][c+3]=us[3];
      if (t < HD) egl[t] = G_egl[(size_t)cid*HD + t];
    }
    __syncthreads();   // B0

    {
      f32x4 acc1;
      #pragma unroll
      for (int v=0;v<4;v++) acc1[v]=0.f;
      #pragma unroll
      for (int ks=0; ks<4; ++ks){
        const int k0 = ks*32;
        short8 af = *(const short8*)&wqL[R+lane16][k0 + quad*8];
        short8 bfr;
        #pragma unroll
        for (int j2=0;j2<8;j2++) bfr[j2] = bts(Sf[lane16][k0 + quad*8 + j2]);
        acc1 = __builtin_amdgcn_mfma_f32_16x16x32_bf16(af, bfr, acc1, 0,0,0);
      }
      #pragma unroll
      for (int v=0;v<4;v++){
        int j = R + quad*4 + v;
        float x = b2f(uL[j][lane16]) - acc1[v];
        vnT[lane16][j] = f2b(x);
      }
    }
    __syncthreads();   // B1

    #pragma unroll
    for (int it=0; it<4; ++it){
      int e = (t + 256*it)*8;
      int r = e >> 7, d = e & 127;
      *(float4*)&wqL[r][d] = qgr[it];
    }
    __syncthreads();   // B2

    {
      f32x4 acc2;
      #pragma unroll
      for (int v=0;v<4;v++) acc2[v]=0.f;
      #pragma unroll
      for (int ks=0; ks<2; ++ks){
        const int k0 = ks*32;
        short8 af = *(const short8*)&ashL[R+lane16][k0 + quad*8];
        short8 bfr = *(const short8*)&vnT[lane16][k0 + quad*8];
        acc2 = __builtin_amdgcn_mfma_f32_16x16x32_bf16(af, bfr, acc2, 0,0,0);
      }
      #pragma unroll
      for (int ks=0; ks<4; ++ks){
        const int k0 = ks*32;
        short8 af = *(const short8*)&wqL[R+lane16][k0 + quad*8];
        short8 bfr;
        #pragma unroll
        for (int j2=0;j2<8;j2++) bfr[j2] = bts(Sf[lane16][k0 + quad*8 + j2]);
        acc2 = __builtin_amdgcn_mfma_f32_16x16x32_bf16(af, bfr, acc2, 0,0,0);
      }
      #pragma unroll
      for (int v=0;v<4;v++){
        size_t row = (size_t)(icg*CHK) + R + quad*4 + v;
        P_CORE[row*C2 + h*HD + c0 + lane16] = f2b(acc2[v]);
      }
    }
    {
      f32x4 accS[2];
      #pragma unroll
      for (int p=0;p<2;p++)
        #pragma unroll
        for (int v=0;v<4;v++) accS[p][v]=0.f;
      #pragma unroll
      for (int p=0;p<2;p++){
        const int dt = wv*2 + p;
        #pragma unroll
        for (int ks=0; ks<2; ++ks){
          const int k0 = ks*32;
          short8 af = *(const short8*)&ktL[dt*16 + lane16][k0 + quad*8];
          short8 bfr = *(const short8*)&vnT[lane16][k0 + quad*8];
          accS[p] = __builtin_amdgcn_mfma_f32_16x16x32_bf16(af, bfr, accS[p], 0,0,0);
        }
      }
      __syncthreads();  // B3
      #pragma unroll
      for (int p=0;p<2;p++){
        #pragma unroll
        for (int v=0;v<4;v++){
          int d = (wv*2+p)*16 + quad*4 + v;
          Sf[lane16][d] = Sf[lane16][d]*egl[d] + accS[p][v];
        }
      }
    }
  }
}

// RMSNorm + rms_scale + sigmoid(gate): core,gate -> opre. Grid TOT.
__global__ void __launch_bounds__(256) rms_gate_k(const float* __restrict__ rms)
{
  __shared__ float part[256];
  __shared__ float scal[16];
  const int t = threadIdx.x;
  const size_t tok = blockIdx.x;
  const int c0 = t*8;
  float v[8];
  const bf16* cr = P_CORE + tok*C2 + c0;
  #pragma unroll
  for (int u=0;u<8;u++) v[u] = b2f(cr[u]);
  float ss=0.f;
  #pragma unroll
  for (int u=0;u<8;u++) ss += v[u]*v[u];
  part[t]=ss; __syncthreads();
  if (t<16){
    float s2=0.f;
    for (int i=0;i<16;i++) s2 += part[t*16+i];
    scal[t] = rsqrtf(s2*(1.f/HD) + 1e-5f);
  }
  __syncthreads();
  float sc = scal[t>>4];
  const bf16* gr = P_GATE + tok*C2 + c0;
  bf16* orow = P_OPRE + tok*C2 + c0;
  #pragma unroll
  for (int u=0;u<8;u++){
    int d = (c0+u)&127;
    float gv = b2f(gr[u]);
    float x = v[u]*sc*rms[d];
    x *= 1.f/(1.f+__expf(-gv));
    orow[u] = f2b(x);
  }
}

// ---------------------------------------------------------------------------
extern "C" void kernel_launch(void* const* d_in, const int* in_sizes, int n_in,
                              void* d_out, int out_size, void* d_ws, size_t ws_size,
                              hipStream_t stream)
{
  const float* x     = (const float*)d_in[0];
  const float* Wq    = (const float*)d_in[1];
  const float* Wk    = (const float*)d_in[2];
  const float* Wv    = (const float*)d_in[3];
  const float* convq = (const float*)d_in[4];
  const float* convk = (const float*)d_in[5];
  const float* convv = (const float*)d_in[6];
  const float* Wb    = (const float*)d_in[7];
  const float* Wfa   = (const float*)d_in[8];
  const float* Wfb   = (const float*)d_in[9];
  const float* Wga   = (const float*)d_in[10];
  const float* Wgb   = (const float*)d_in[11];
  const float* bgb   = (const float*)d_in[12];
  const float* A_log = (const float*)d_in[13];
  const float* dtb   = (const float*)d_in[14];
  const float* rms   = (const float*)d_in[15];
  const float* Wo    = (const float*)d_in[16];
  (void)d_ws; (void)ws_size;

  dim3 gM(16, TOT/128);          // (16,64)
  dim3 gN(16, TOT/128);

  // weight prep
  wtrans_k<<<dim3(32,32), 256, 0, stream>>>(Wq,  0, -1, C2,  C2);
  wtrans_k<<<dim3(32,32), 256, 0, stream>>>(Wk,  1, -1, C2,  C2);
  wtrans_k<<<dim3(32,32), 256, 0, stream>>>(Wv,  2, -1, C2,  C2);
  wtrans_k<<<dim3(32,32), 256, 0, stream>>>(Wo,  3, -1, C2,  C2);
  wtrans_k<<<dim3(2,32),  256, 0, stream>>>(Wga, 4, -1, HD,  C2);
  wtrans_k<<<dim3(1,32),  256, 0, stream>>>(Wb,  5, -1, NHD, C2);
  wtrans_k<<<dim3(2,32),  256, 0, stream>>>(Wfa, 6,  7, HD,  C2);
  wtrans_k<<<dim3(32,2),  256, 0, stream>>>(Wfb, 8,  9, C2,  HD);
  wtrans_k<<<dim3(32,2),  256, 0, stream>>>(Wgb, 10,-1, C2,  HD);

  xconv_k<<<TOT*C2/(256*8), 256, 0, stream>>>(x);

  gemm_mfma<0><<<gM, 256, 0, stream>>>(0, 0, 0, nullptr, C2);
  gemm_mfma<0><<<gM, 256, 0, stream>>>(0, 1, 1, nullptr, C2);
  gemm_mfma<0><<<gM, 256, 0, stream>>>(0, 2, 2, nullptr, C2);

  thinx_k<<<TOT/32, 256, 0, stream>>>();     // beta, fa(hi/lo), ga

  conv_silu_k<<<TOT, 256, 0, stream>>>(0, convq, 1);
  conv_silu_k<<<TOT, 256, 0, stream>>>(1, convk, 1);
  conv_silu_k<<<TOT, 256, 0, stream>>>(2, convv, 0);

  glin_k<<<gN, 256, 0, stream>>>(dtb);
  g_transform_k<<<(TOT*C2)/256, 256, 0, stream>>>(A_log);
  gcum_k<<<2048, 128, 0, stream>>>();

  stage1_k<<<2048, 512, 0, stream>>>();
  stage2_k<<<256, 256, 0, stream>>>();

  gate_k<<<gN, 256, 0, stream>>>(bgb);
  rms_gate_k<<<TOT, 256, 0, stream>>>(rms);

  gemm_mfma<1><<<gM, 256, 0, stream>>>(1, 3, -1, (float*)d_out, C2);
}